// Round 1
// baseline (314.716 us; speedup 1.0000x reference)
//
#include <hip/hip_runtime.h>

#define NH   8
#define NPTS 4
#define BB   8
#define CCH  256
#define HH   64
#define WW   64
#define NPIX 4096   // H*W
#define DH   32     // C/NH

// ---------------------------------------------------------------------------
// Kernel A: ow = q @ W_off + b_off, softmax over points, emit per-sample
// (xpix, ypix, weight) as float4.  Block = 64 pixels, 256 threads.
// Wave w (=jg) owns output columns j0..j0+23 (= heads 2*jg, 2*jg+1).
// ---------------------------------------------------------------------------
__global__ __launch_bounds__(256)
void kA_offsets(const float* __restrict__ query, const float* __restrict__ W_off,
                const float* __restrict__ b_off, float4* __restrict__ coords)
{
    __shared__ float q_lds[64][64];   // [k][pixel]
    __shared__ float w_lds[64][96];   // [k][j]

    const int t  = threadIdx.x;
    const int g0 = blockIdx.x * 64;        // global pixel base (b*NPIX + n)
    const int b  = g0 >> 12;               // / NPIX
    const int n0 = g0 & (NPIX - 1);
    const float* qbase = query + (size_t)b * CCH * NPIX;

    const int px = t & 63;
    const int jg = t >> 6;                 // wave id 0..3
    const int j0 = jg * 24;

    float acc[24];
#pragma unroll
    for (int i = 0; i < 24; ++i) acc[i] = 0.f;

    for (int kc = 0; kc < CCH; kc += 64) {
        // stage q tile: q_lds[k][px] = query[b, kc+k, n0+px]
        const int p4 = (t & 15) << 2;
        const int k0 = t >> 4;
#pragma unroll
        for (int kk = 0; kk < 64; kk += 16) {
            float4 v = *(const float4*)(qbase + (size_t)(kc + k0 + kk) * NPIX + (n0 + p4));
            *(float4*)&q_lds[k0 + kk][p4] = v;
        }
        // stage W_off tile: w_lds[k][j], 64 rows x 96
#pragma unroll
        for (int ii = 0; ii < 6; ++ii) {
            int i4 = t + ii * 256;         // 0..1535 float4 slots
            int k  = i4 / 24;
            int j4 = i4 - k * 24;
            *(float4*)&w_lds[k][j4 << 2] =
                *(const float4*)(W_off + (size_t)(kc + k) * 96 + (j4 << 2));
        }
        __syncthreads();
#pragma unroll 8
        for (int k = 0; k < 64; ++k) {
            float a = q_lds[k][px];
#pragma unroll
            for (int j4 = 0; j4 < 6; ++j4) {
                float4 w = *(const float4*)&w_lds[k][j0 + (j4 << 2)]; // wave-broadcast
                acc[j4 * 4 + 0] = fmaf(a, w.x, acc[j4 * 4 + 0]);
                acc[j4 * 4 + 1] = fmaf(a, w.y, acc[j4 * 4 + 1]);
                acc[j4 * 4 + 2] = fmaf(a, w.z, acc[j4 * 4 + 2]);
                acc[j4 * 4 + 3] = fmaf(a, w.w, acc[j4 * 4 + 3]);
            }
        }
        __syncthreads();
    }

    // epilogue: per thread, 2 heads x 4 points
    const int n = n0 + px;
    const int x = n & 63;
    const int y = n >> 6;
    const float fx = (float)x, fy = (float)y;

#pragma unroll
    for (int hh = 0; hh < 2; ++hh) {
        const int head = jg * 2 + hh;
        const int lb   = hh * 12;
        float ox[4], oy[4], l[4];
#pragma unroll
        for (int p = 0; p < 4; ++p) {
            ox[p] = acc[lb + p * 3 + 0] + b_off[j0 + lb + p * 3 + 0];
            oy[p] = acc[lb + p * 3 + 1] + b_off[j0 + lb + p * 3 + 1];
            l[p]  = acc[lb + p * 3 + 2] + b_off[j0 + lb + p * 3 + 2];
        }
        float m = fmaxf(fmaxf(l[0], l[1]), fmaxf(l[2], l[3]));
        float e[4], s = 0.f;
#pragma unroll
        for (int p = 0; p < 4; ++p) { e[p] = __expf(l[p] - m); s += e[p]; }
        float inv = 1.f / s;
        float4* cp = coords + ((size_t)(b * NPIX + n) * NH + head) * NPTS;
#pragma unroll
        for (int p = 0; p < 4; ++p) {
            // xpix = x + ox*0.1*31.5 ; ypix = y + oy*0.1*31.5
            cp[p] = make_float4(fx + ox[p] * 3.15f, fy + oy[p] * 3.15f, e[p] * inv, 0.f);
        }
    }
}

// ---------------------------------------------------------------------------
// Kernel B: bilinear gather + weighted sum over points.
// Block = one (b, head, row y); 4 waves = 4 channel-groups of 8; lane = x.
// ---------------------------------------------------------------------------
__global__ __launch_bounds__(256)
void kB_sample(const float* __restrict__ key, const float4* __restrict__ coords,
               float* __restrict__ feat)
{
    __shared__ float cx[4][64], cy[4][64], cw[4][64];

    const int t = threadIdx.x;
    int bi = blockIdx.x;                   // B*NH*H = 4096
    const int y    = bi & 63; bi >>= 6;
    const int head = bi & 7;  bi >>= 3;
    const int b    = bi;

    {   // stage the row's coords: 64 px * 4 pts
        const int xx = t >> 2, pt = t & 3;
        float4 v = coords[((size_t)(b * NPIX + y * WW + xx) * NH + head) * NPTS + pt];
        cx[pt][xx] = v.x; cy[pt][xx] = v.y; cw[pt][xx] = v.z;
    }
    __syncthreads();

    const int x  = t & 63;
    const int cg = t >> 6;
    const int c0 = head * DH + cg * 8;
    const float* kbase = key + ((size_t)b * CCH + c0) * NPIX;

    float acc[8];
#pragma unroll
    for (int i = 0; i < 8; ++i) acc[i] = 0.f;

#pragma unroll
    for (int pt = 0; pt < 4; ++pt) {
        float xp = cx[pt][x], yp = cy[pt][x], wgt = cw[pt][x];
        float x0f = floorf(xp), y0f = floorf(yp);
        int   x0  = (int)x0f,  y0  = (int)y0f;
        float wx  = xp - x0f,  wy  = yp - y0f;
#pragma unroll
        for (int cr = 0; cr < 4; ++cr) {
            int   xi = x0 + (cr & 1);
            int   yi = y0 + (cr >> 1);
            float wc = ((cr & 1) ? wx : 1.f - wx) * ((cr >> 1) ? wy : 1.f - wy);
            bool  valid = (xi >= 0) && (xi < WW) && (yi >= 0) && (yi < HH);
            int   xc = min(max(xi, 0), WW - 1);
            int   yc = min(max(yi, 0), HH - 1);
            const float* p = kbase + yc * WW + xc;
            float ww = valid ? (wgt * wc) : 0.f;
#pragma unroll
            for (int c = 0; c < 8; ++c)
                acc[c] = fmaf(ww, p[(size_t)c * NPIX], acc[c]);
        }
    }

    float* fp = feat + (size_t)(b * NPIX + y * WW + x) * CCH + c0;
    *(float4*)fp       = make_float4(acc[0], acc[1], acc[2], acc[3]);
    *(float4*)(fp + 4) = make_float4(acc[4], acc[5], acc[6], acc[7]);
}

// ---------------------------------------------------------------------------
// Kernel C: out = feat @ W_proj + b_proj.  fp32 SGEMM, 64x64 tile, K-chunk 32.
// Thread computes 4x4 outputs.
// ---------------------------------------------------------------------------
__global__ __launch_bounds__(256)
void kC_proj(const float* __restrict__ feat, const float* __restrict__ W_proj,
             const float* __restrict__ b_proj, float* __restrict__ out)
{
    __shared__ float a_lds[32][64];   // [k][m] (transposed store)
    __shared__ float b_lds[32][64];   // [k][n]

    const int t  = threadIdx.x;
    const int mb = blockIdx.x >> 2;   // 512 m-tiles (n fast for feat-tile L2 reuse)
    const int nb = blockIdx.x & 3;
    const int m0 = mb * 64, n0 = nb * 64;

    const int tm = t >> 4, tn = t & 15;
    const int r  = t >> 2, qa = t & 3;   // a-tile loader mapping
    const int kb = t >> 3, qb = t & 7;   // b-tile loader mapping

    float acc[4][4];
#pragma unroll
    for (int i = 0; i < 4; ++i)
#pragma unroll
        for (int j = 0; j < 4; ++j) acc[i][j] = 0.f;

    for (int kc = 0; kc < 256; kc += 32) {
        const float* ap = feat + (size_t)(m0 + r) * 256 + kc + (qa << 2);
        float4 a0 = *(const float4*)ap;
        float4 a1 = *(const float4*)(ap + 16);
        const float* bp = W_proj + (size_t)(kc + kb) * 256 + n0 + (qb << 2);
        float4 w0 = *(const float4*)bp;
        float4 w1 = *(const float4*)(bp + 32);
        __syncthreads();   // previous chunk's compute done before overwrite
        a_lds[(qa << 2) + 0][r] = a0.x;
        a_lds[(qa << 2) + 1][r] = a0.y;
        a_lds[(qa << 2) + 2][r] = a0.z;
        a_lds[(qa << 2) + 3][r] = a0.w;
        a_lds[16 + (qa << 2) + 0][r] = a1.x;
        a_lds[16 + (qa << 2) + 1][r] = a1.y;
        a_lds[16 + (qa << 2) + 2][r] = a1.z;
        a_lds[16 + (qa << 2) + 3][r] = a1.w;
        *(float4*)&b_lds[kb][(qb << 2)]      = w0;
        *(float4*)&b_lds[kb][(qb << 2) + 32] = w1;
        __syncthreads();
#pragma unroll
        for (int k = 0; k < 32; ++k) {
            float4 av = *(const float4*)&a_lds[k][tm << 2];
            float4 bv = *(const float4*)&b_lds[k][tn << 2];
            acc[0][0] = fmaf(av.x, bv.x, acc[0][0]);
            acc[0][1] = fmaf(av.x, bv.y, acc[0][1]);
            acc[0][2] = fmaf(av.x, bv.z, acc[0][2]);
            acc[0][3] = fmaf(av.x, bv.w, acc[0][3]);
            acc[1][0] = fmaf(av.y, bv.x, acc[1][0]);
            acc[1][1] = fmaf(av.y, bv.y, acc[1][1]);
            acc[1][2] = fmaf(av.y, bv.z, acc[1][2]);
            acc[1][3] = fmaf(av.y, bv.w, acc[1][3]);
            acc[2][0] = fmaf(av.z, bv.x, acc[2][0]);
            acc[2][1] = fmaf(av.z, bv.y, acc[2][1]);
            acc[2][2] = fmaf(av.z, bv.z, acc[2][2]);
            acc[2][3] = fmaf(av.z, bv.w, acc[2][3]);
            acc[3][0] = fmaf(av.w, bv.x, acc[3][0]);
            acc[3][1] = fmaf(av.w, bv.y, acc[3][1]);
            acc[3][2] = fmaf(av.w, bv.z, acc[3][2]);
            acc[3][3] = fmaf(av.w, bv.w, acc[3][3]);
        }
    }

    const float4 bp4 = *(const float4*)(b_proj + n0 + (tn << 2));
#pragma unroll
    for (int i = 0; i < 4; ++i) {
        float4 o = make_float4(acc[i][0] + bp4.x, acc[i][1] + bp4.y,
                               acc[i][2] + bp4.z, acc[i][3] + bp4.w);
        *(float4*)(out + (size_t)(m0 + (tm << 2) + i) * 256 + n0 + (tn << 2)) = o;
    }
}

// ---------------------------------------------------------------------------
extern "C" void kernel_launch(void* const* d_in, const int* in_sizes, int n_in,
                              void* d_out, int out_size, void* d_ws, size_t ws_size,
                              hipStream_t stream)
{
    const float* query  = (const float*)d_in[0];
    const float* key    = (const float*)d_in[1];
    const float* W_off  = (const float*)d_in[2];
    const float* b_off  = (const float*)d_in[3];
    const float* W_proj = (const float*)d_in[4];
    const float* b_proj = (const float*)d_in[5];
    float* out = (float*)d_out;

    // workspace layout: coords float4[B*N*NH*NPTS] (16.8 MB) then feat (33.5 MB)
    float4* coords = (float4*)d_ws;
    float*  feat   = (float*)((char*)d_ws + (size_t)BB * NPIX * NH * NPTS * sizeof(float4));

    kA_offsets<<<(BB * NPIX) / 64, 256, 0, stream>>>(query, W_off, b_off, coords);
    kB_sample<<<BB * NH * HH, 256, 0, stream>>>(key, coords, feat);
    kC_proj<<<(BB * NPIX / 64) * (CCH / 64), 256, 0, stream>>>(feat, W_proj, b_proj, out);
}

// Round 2
// 253.028 us; speedup vs baseline: 1.2438x; 1.2438x over previous
//
#include <hip/hip_runtime.h>

#define NH   8
#define NPTS 4
#define BB   8
#define CCH  256
#define HH   64
#define WW   64
#define NPIX 4096   // H*W
#define DH   32     // C/NH

// ---------------------------------------------------------------------------
// Kernel A: ow = q @ W_off + b_off, softmax over points, emit per-sample
// (xpix, ypix, weight) as float4.  Block = 64 pixels, 256 threads.
// ---------------------------------------------------------------------------
__global__ __launch_bounds__(256)
void kA_offsets(const float* __restrict__ query, const float* __restrict__ W_off,
                const float* __restrict__ b_off, float4* __restrict__ coords)
{
    __shared__ float q_lds[64][64];   // [k][pixel]
    __shared__ float w_lds[64][96];   // [k][j]

    const int t  = threadIdx.x;
    const int g0 = blockIdx.x * 64;        // global pixel base (b*NPIX + n)
    const int b  = g0 >> 12;               // / NPIX
    const int n0 = g0 & (NPIX - 1);
    const float* qbase = query + (size_t)b * CCH * NPIX;

    const int px = t & 63;
    const int jg = t >> 6;                 // wave id 0..3
    const int j0 = jg * 24;

    float acc[24];
#pragma unroll
    for (int i = 0; i < 24; ++i) acc[i] = 0.f;

    for (int kc = 0; kc < CCH; kc += 64) {
        const int p4 = (t & 15) << 2;
        const int k0 = t >> 4;
#pragma unroll
        for (int kk = 0; kk < 64; kk += 16) {
            float4 v = *(const float4*)(qbase + (size_t)(kc + k0 + kk) * NPIX + (n0 + p4));
            *(float4*)&q_lds[k0 + kk][p4] = v;
        }
#pragma unroll
        for (int ii = 0; ii < 6; ++ii) {
            int i4 = t + ii * 256;
            int k  = i4 / 24;
            int j4 = i4 - k * 24;
            *(float4*)&w_lds[k][j4 << 2] =
                *(const float4*)(W_off + (size_t)(kc + k) * 96 + (j4 << 2));
        }
        __syncthreads();
#pragma unroll 8
        for (int k = 0; k < 64; ++k) {
            float a = q_lds[k][px];
#pragma unroll
            for (int j4 = 0; j4 < 6; ++j4) {
                float4 w = *(const float4*)&w_lds[k][j0 + (j4 << 2)];
                acc[j4 * 4 + 0] = fmaf(a, w.x, acc[j4 * 4 + 0]);
                acc[j4 * 4 + 1] = fmaf(a, w.y, acc[j4 * 4 + 1]);
                acc[j4 * 4 + 2] = fmaf(a, w.z, acc[j4 * 4 + 2]);
                acc[j4 * 4 + 3] = fmaf(a, w.w, acc[j4 * 4 + 3]);
            }
        }
        __syncthreads();
    }

    const int n = n0 + px;
    const int x = n & 63;
    const int y = n >> 6;
    const float fx = (float)x, fy = (float)y;

#pragma unroll
    for (int hh = 0; hh < 2; ++hh) {
        const int head = jg * 2 + hh;
        const int lb   = hh * 12;
        float ox[4], oy[4], l[4];
#pragma unroll
        for (int p = 0; p < 4; ++p) {
            ox[p] = acc[lb + p * 3 + 0] + b_off[j0 + lb + p * 3 + 0];
            oy[p] = acc[lb + p * 3 + 1] + b_off[j0 + lb + p * 3 + 1];
            l[p]  = acc[lb + p * 3 + 2] + b_off[j0 + lb + p * 3 + 2];
        }
        float m = fmaxf(fmaxf(l[0], l[1]), fmaxf(l[2], l[3]));
        float e[4], s = 0.f;
#pragma unroll
        for (int p = 0; p < 4; ++p) { e[p] = __expf(l[p] - m); s += e[p]; }
        float inv = 1.f / s;
        float4* cp = coords + ((size_t)(b * NPIX + n) * NH + head) * NPTS;
#pragma unroll
        for (int p = 0; p < 4; ++p) {
            cp[p] = make_float4(fx + ox[p] * 3.15f, fy + oy[p] * 3.15f, e[p] * inv, 0.f);
        }
    }
}

// ---------------------------------------------------------------------------
// Kernel T: transpose key [b][c][n] -> keyT [b][n][c]  (channel-last)
// ---------------------------------------------------------------------------
__global__ __launch_bounds__(256)
void kT_transpose(const float* __restrict__ key, float* __restrict__ keyT)
{
    __shared__ float tile[64][65];
    int bid = blockIdx.x;                  // B*4*64 = 2048
    const int nt = bid & 63; bid >>= 6;
    const int ct = bid & 3;  bid >>= 2;
    const int b  = bid;
    const int n0 = nt * 64, c0 = ct * 64;
    const int t = threadIdx.x;

    const float* src = key + ((size_t)b * CCH + c0) * NPIX + n0;
#pragma unroll
    for (int ii = 0; ii < 4; ++ii) {
        int idx = t + ii * 256;
        int cc = idx >> 4, q = idx & 15;
        float4 v = *(const float4*)(src + (size_t)cc * NPIX + (q << 2));
        tile[cc][(q << 2) + 0] = v.x;
        tile[cc][(q << 2) + 1] = v.y;
        tile[cc][(q << 2) + 2] = v.z;
        tile[cc][(q << 2) + 3] = v.w;
    }
    __syncthreads();
    float* dst = keyT + ((size_t)(b * NPIX + n0)) * CCH + c0;
#pragma unroll
    for (int ii = 0; ii < 4; ++ii) {
        int idx = t + ii * 256;
        int nn = idx >> 4, q = idx & 15;
        float4 v = make_float4(tile[(q << 2) + 0][nn], tile[(q << 2) + 1][nn],
                               tile[(q << 2) + 2][nn], tile[(q << 2) + 3][nn]);
        *(float4*)(dst + (size_t)nn * CCH + (q << 2)) = v;
    }
}

// ---------------------------------------------------------------------------
// Kernel B (new): channel-last gather.  Wave = 1 pixel x 8 heads; lanegroup
// of 8 lanes per head, each lane owns 4 channels (float4).  No LDS, no sync.
// ---------------------------------------------------------------------------
__global__ __launch_bounds__(256)
void kB_gather(const float* __restrict__ keyT, const float4* __restrict__ coords,
               float* __restrict__ feat)
{
    // XCD-chunked swizzle: 8192 blocks -> each XCD gets a contiguous pixel range
    const int bid  = blockIdx.x;
    const int sbid = (bid & 7) * 1024 + (bid >> 3);

    const int t  = threadIdx.x;
    const int wv = t >> 6, l = t & 63;
    const int g  = sbid * 4 + wv;          // global pixel id, 0..32767
    const int b  = g >> 12;
    const int head = l >> 3;
    const int cl   = (l & 7) << 2;
    const int c    = head * DH + cl;

    const float*  kb = keyT + (((size_t)b << 12)) * CCH;
    const float4* cp = coords + ((size_t)g * NH + head) * NPTS;

    float4 acc = make_float4(0.f, 0.f, 0.f, 0.f);
#pragma unroll
    for (int pt = 0; pt < 4; ++pt) {
        float4 co = cp[pt];
        float xp = co.x, yp = co.y, wgt = co.z;
        float x0f = floorf(xp), y0f = floorf(yp);
        int   x0  = (int)x0f,  y0  = (int)y0f;
        float wx  = xp - x0f,  wy  = yp - y0f;
#pragma unroll
        for (int cr = 0; cr < 4; ++cr) {
            int   xi = x0 + (cr & 1);
            int   yi = y0 + (cr >> 1);
            float wc = ((cr & 1) ? wx : 1.f - wx) * ((cr >> 1) ? wy : 1.f - wy);
            bool  valid = (xi >= 0) && (xi < WW) && (yi >= 0) && (yi < HH);
            int   xc = min(max(xi, 0), WW - 1);
            int   yc = min(max(yi, 0), HH - 1);
            float ww = valid ? (wgt * wc) : 0.f;
            float4 v = *(const float4*)(kb + ((size_t)((yc << 6) + xc)) * CCH + c);
            acc.x = fmaf(ww, v.x, acc.x);
            acc.y = fmaf(ww, v.y, acc.y);
            acc.z = fmaf(ww, v.z, acc.z);
            acc.w = fmaf(ww, v.w, acc.w);
        }
    }
    *(float4*)(feat + (size_t)g * CCH + c) = acc;
}

// ---------------------------------------------------------------------------
// Kernel B (fallback, round-1 proven): scalar strided gather from original key
// ---------------------------------------------------------------------------
__global__ __launch_bounds__(256)
void kB_sample(const float* __restrict__ key, const float4* __restrict__ coords,
               float* __restrict__ feat)
{
    __shared__ float cx[4][64], cy[4][64], cw[4][64];

    const int t = threadIdx.x;
    int bi = blockIdx.x;
    const int y    = bi & 63; bi >>= 6;
    const int head = bi & 7;  bi >>= 3;
    const int b    = bi;

    {
        const int xx = t >> 2, pt = t & 3;
        float4 v = coords[((size_t)(b * NPIX + y * WW + xx) * NH + head) * NPTS + pt];
        cx[pt][xx] = v.x; cy[pt][xx] = v.y; cw[pt][xx] = v.z;
    }
    __syncthreads();

    const int x  = t & 63;
    const int cg = t >> 6;
    const int c0 = head * DH + cg * 8;
    const float* kbase = key + ((size_t)b * CCH + c0) * NPIX;

    float acc[8];
#pragma unroll
    for (int i = 0; i < 8; ++i) acc[i] = 0.f;

#pragma unroll
    for (int pt = 0; pt < 4; ++pt) {
        float xp = cx[pt][x], yp = cy[pt][x], wgt = cw[pt][x];
        float x0f = floorf(xp), y0f = floorf(yp);
        int   x0  = (int)x0f,  y0  = (int)y0f;
        float wx  = xp - x0f,  wy  = yp - y0f;
#pragma unroll
        for (int cr = 0; cr < 4; ++cr) {
            int   xi = x0 + (cr & 1);
            int   yi = y0 + (cr >> 1);
            float wc = ((cr & 1) ? wx : 1.f - wx) * ((cr >> 1) ? wy : 1.f - wy);
            bool  valid = (xi >= 0) && (xi < WW) && (yi >= 0) && (yi < HH);
            int   xc = min(max(xi, 0), WW - 1);
            int   yc = min(max(yi, 0), HH - 1);
            const float* p = kbase + yc * WW + xc;
            float ww = valid ? (wgt * wc) : 0.f;
#pragma unroll
            for (int c = 0; c < 8; ++c)
                acc[c] = fmaf(ww, p[(size_t)c * NPIX], acc[c]);
        }
    }

    float* fp = feat + (size_t)(b * NPIX + y * WW + x) * CCH + c0;
    *(float4*)fp       = make_float4(acc[0], acc[1], acc[2], acc[3]);
    *(float4*)(fp + 4) = make_float4(acc[4], acc[5], acc[6], acc[7]);
}

// ---------------------------------------------------------------------------
// Kernel C: out = feat @ W_proj + b_proj.  64x128 tile, 4x8 per thread.
// Thread's n-cols split {4tn, 64+4tn} so bv LDS reads are 2-way (free).
// ---------------------------------------------------------------------------
__global__ __launch_bounds__(256)
void kC_proj(const float* __restrict__ feat, const float* __restrict__ W_proj,
             const float* __restrict__ b_proj, float* __restrict__ out)
{
    __shared__ float a_lds[32][64];    // [k][m]
    __shared__ float b_lds[32][128];   // [k][n]

    const int t  = threadIdx.x;
    const int mb = blockIdx.x >> 1;    // 512 m-tiles
    const int nb = blockIdx.x & 1;     // 2 n-tiles
    const int m0 = mb * 64, n0 = nb * 128;

    const int tm = t >> 4, tn = t & 15;

    float acc[4][8];
#pragma unroll
    for (int i = 0; i < 4; ++i)
#pragma unroll
        for (int j = 0; j < 8; ++j) acc[i][j] = 0.f;

    for (int kc = 0; kc < 256; kc += 32) {
        // A: 64 rows x 8 k-quads = 512 float4 / 256 thr = 2 each
        float4 a[2];
#pragma unroll
        for (int ii = 0; ii < 2; ++ii) {
            int idx = t + ii * 256;
            int r = idx >> 3, q = idx & 7;
            a[ii] = *(const float4*)(feat + (size_t)(m0 + r) * 256 + kc + (q << 2));
        }
        // B: 32 k x 32 n-quads = 1024 float4 / 256 thr = 4 each
        float4 w[4];
#pragma unroll
        for (int ii = 0; ii < 4; ++ii) {
            int idx = t + ii * 256;
            int kk = idx >> 5, q = idx & 31;
            w[ii] = *(const float4*)(W_proj + (size_t)(kc + kk) * 256 + n0 + (q << 2));
        }
        __syncthreads();   // previous chunk fully consumed
#pragma unroll
        for (int ii = 0; ii < 2; ++ii) {
            int idx = t + ii * 256;
            int r = idx >> 3, q = idx & 7;
            a_lds[(q << 2) + 0][r] = a[ii].x;
            a_lds[(q << 2) + 1][r] = a[ii].y;
            a_lds[(q << 2) + 2][r] = a[ii].z;
            a_lds[(q << 2) + 3][r] = a[ii].w;
        }
#pragma unroll
        for (int ii = 0; ii < 4; ++ii) {
            int idx = t + ii * 256;
            int kk = idx >> 5, q = idx & 31;
            *(float4*)&b_lds[kk][q << 2] = w[ii];
        }
        __syncthreads();
#pragma unroll
        for (int k = 0; k < 32; ++k) {
            float4 av  = *(const float4*)&a_lds[k][tm << 2];
            float4 bv0 = *(const float4*)&b_lds[k][tn << 2];
            float4 bv1 = *(const float4*)&b_lds[k][64 + (tn << 2)];
            acc[0][0] = fmaf(av.x, bv0.x, acc[0][0]);
            acc[0][1] = fmaf(av.x, bv0.y, acc[0][1]);
            acc[0][2] = fmaf(av.x, bv0.z, acc[0][2]);
            acc[0][3] = fmaf(av.x, bv0.w, acc[0][3]);
            acc[0][4] = fmaf(av.x, bv1.x, acc[0][4]);
            acc[0][5] = fmaf(av.x, bv1.y, acc[0][5]);
            acc[0][6] = fmaf(av.x, bv1.z, acc[0][6]);
            acc[0][7] = fmaf(av.x, bv1.w, acc[0][7]);
            acc[1][0] = fmaf(av.y, bv0.x, acc[1][0]);
            acc[1][1] = fmaf(av.y, bv0.y, acc[1][1]);
            acc[1][2] = fmaf(av.y, bv0.z, acc[1][2]);
            acc[1][3] = fmaf(av.y, bv0.w, acc[1][3]);
            acc[1][4] = fmaf(av.y, bv1.x, acc[1][4]);
            acc[1][5] = fmaf(av.y, bv1.y, acc[1][5]);
            acc[1][6] = fmaf(av.y, bv1.z, acc[1][6]);
            acc[1][7] = fmaf(av.y, bv1.w, acc[1][7]);
            acc[2][0] = fmaf(av.z, bv0.x, acc[2][0]);
            acc[2][1] = fmaf(av.z, bv0.y, acc[2][1]);
            acc[2][2] = fmaf(av.z, bv0.z, acc[2][2]);
            acc[2][3] = fmaf(av.z, bv0.w, acc[2][3]);
            acc[2][4] = fmaf(av.z, bv1.x, acc[2][4]);
            acc[2][5] = fmaf(av.z, bv1.y, acc[2][5]);
            acc[2][6] = fmaf(av.z, bv1.z, acc[2][6]);
            acc[2][7] = fmaf(av.z, bv1.w, acc[2][7]);
            acc[3][0] = fmaf(av.w, bv0.x, acc[3][0]);
            acc[3][1] = fmaf(av.w, bv0.y, acc[3][1]);
            acc[3][2] = fmaf(av.w, bv0.z, acc[3][2]);
            acc[3][3] = fmaf(av.w, bv0.w, acc[3][3]);
            acc[3][4] = fmaf(av.w, bv1.x, acc[3][4]);
            acc[3][5] = fmaf(av.w, bv1.y, acc[3][5]);
            acc[3][6] = fmaf(av.w, bv1.z, acc[3][6]);
            acc[3][7] = fmaf(av.w, bv1.w, acc[3][7]);
        }
        __syncthreads();   // keep loaders from racing next chunk into LDS
    }

    const float4 bp0 = *(const float4*)(b_proj + n0 + (tn << 2));
    const float4 bp1 = *(const float4*)(b_proj + n0 + 64 + (tn << 2));
#pragma unroll
    for (int i = 0; i < 4; ++i) {
        float* op = out + (size_t)(m0 + (tm << 2) + i) * 256 + n0;
        *(float4*)(op + (tn << 2)) =
            make_float4(acc[i][0] + bp0.x, acc[i][1] + bp0.y,
                        acc[i][2] + bp0.z, acc[i][3] + bp0.w);
        *(float4*)(op + 64 + (tn << 2)) =
            make_float4(acc[i][4] + bp1.x, acc[i][5] + bp1.y,
                        acc[i][6] + bp1.z, acc[i][7] + bp1.w);
    }
}

// ---------------------------------------------------------------------------
extern "C" void kernel_launch(void* const* d_in, const int* in_sizes, int n_in,
                              void* d_out, int out_size, void* d_ws, size_t ws_size,
                              hipStream_t stream)
{
    const float* query  = (const float*)d_in[0];
    const float* key    = (const float*)d_in[1];
    const float* W_off  = (const float*)d_in[2];
    const float* b_off  = (const float*)d_in[3];
    const float* W_proj = (const float*)d_in[4];
    const float* b_proj = (const float*)d_in[5];
    float* out = (float*)d_out;

    const size_t keyT_bytes   = (size_t)BB * NPIX * CCH * sizeof(float);          // 33.55 MB
    const size_t coords_bytes = (size_t)BB * NPIX * NH * NPTS * sizeof(float4);   // 16.78 MB
    const size_t feat_bytes   = (size_t)BB * NPIX * CCH * sizeof(float);          // 33.55 MB

    if (ws_size >= keyT_bytes + coords_bytes + feat_bytes) {
        float*  keyT   = (float*)d_ws;
        float4* coords = (float4*)((char*)d_ws + keyT_bytes);
        float*  feat   = (float*)((char*)d_ws + keyT_bytes + coords_bytes);

        kA_offsets<<<(BB * NPIX) / 64, 256, 0, stream>>>(query, W_off, b_off, coords);
        kT_transpose<<<BB * 4 * 64, 256, 0, stream>>>(key, keyT);
        kB_gather<<<(BB * NPIX) / 4, 256, 0, stream>>>(keyT, coords, feat);
        kC_proj<<<(BB * NPIX / 64) * 2, 256, 0, stream>>>(feat, W_proj, b_proj, out);
    } else {
        // fallback: round-1 proven path (needs 50.3 MB)
        float4* coords = (float4*)d_ws;
        float*  feat   = (float*)((char*)d_ws + coords_bytes);

        kA_offsets<<<(BB * NPIX) / 64, 256, 0, stream>>>(query, W_off, b_off, coords);
        kB_sample<<<BB * NH * HH, 256, 0, stream>>>(key, coords, feat);
        kC_proj<<<(BB * NPIX / 64) * 2, 256, 0, stream>>>(feat, W_proj, b_proj, out);
    }
}